// Round 5
// baseline (638.241 us; speedup 1.0000x reference)
//
#include <hip/hip_runtime.h>

typedef unsigned short ushort_t;
typedef __bf16 bf16x8 __attribute__((ext_vector_type(8)));
typedef float f32x4 __attribute__((ext_vector_type(4)));

__device__ __forceinline__ ushort_t f2bf(float f) {
    unsigned int u = __float_as_uint(f);
    unsigned int r = (u + 0x7fffu + ((u >> 16) & 1u)) >> 16;
    return (ushort_t)r;
}
__device__ __forceinline__ float bf2f(ushort_t u) {
    return __uint_as_float(((unsigned int)u) << 16);
}
__device__ __forceinline__ float wredsum(float v) {
    for (int o = 32; o; o >>= 1) v += __shfl_xor(v, o, 64);
    return v;
}
__device__ __forceinline__ float logsig(float z) {
    return (z >= 0.f) ? -log1pf(expf(-z)) : (z - log1pf(expf(z)));
}
__device__ __forceinline__ void msmerge(float& m, float& s, float om, float os) {
    float M = fmaxf(m, om);
    s = s * __expf(m - M) + os * __expf(om - M);
    m = M;
}

// ---------------- weight prep: Wov = Wo @ Wv, bvo = Wo@bv + bo ----------------
__global__ void k_wov(const float* __restrict__ Wo, const float* __restrict__ Wv,
                      const float* __restrict__ bvv, const float* __restrict__ bo,
                      ushort_t* __restrict__ Wovb, float* __restrict__ bvo) {
    int o = blockIdx.x, k = threadIdx.x;
    float s = 0.f;
    for (int j = 0; j < 256; ++j) s += Wo[o * 256 + j] * Wv[j * 256 + k];
    Wovb[o * 256 + k] = f2bf(s);
    float pb = Wo[o * 256 + k] * bvv[k];
    pb = wredsum(pb);
    __shared__ float sh[4];
    if ((k & 63) == 0) sh[k >> 6] = pb;
    __syncthreads();
    if (k == 0) bvo[o] = sh[0] + sh[1] + sh[2] + sh[3] + bo[o];
}

__global__ void k_cast_flat(const float* __restrict__ src, ushort_t* __restrict__ dst, int n) {
    int i = blockIdx.x * 256 + threadIdx.x;
    if (i < n) dst[i] = f2bf(src[i]);
}

// x (R,256) fp32 -> cat (R,512) bf16 at cols [0,256)
__global__ void k_cast_x(const float* __restrict__ src, ushort_t* __restrict__ dst) {
    long i = (long)blockIdx.x * 256 + threadIdx.x;
    long r = i >> 8;
    int c = (int)(i & 255);
    dst[r * 512 + c] = f2bf(src[i]);
}

// ---------------- fused adj pass: raw-transpose bf16 + row/col LSE partials ----------------
__global__ void k_prep(const float* __restrict__ adj, ushort_t* __restrict__ At10,
                       float* __restrict__ rowm, float* __restrict__ rows_,
                       float* __restrict__ colm, float* __restrict__ cols_) {
    int b = blockIdx.z;
    int n0 = blockIdx.x * 64, m0 = blockIdx.y * 64;
    __shared__ ushort_t T[64][72];
    int t = threadIdx.x;
    int r16 = t >> 4, cq = t & 15;
    const float* base = adj + ((long)b * 2048 + m0) * 2048 + n0;
#pragma unroll
    for (int p = 0; p < 4; ++p) {
        int row = p * 16 + r16;
        float4 v = *(const float4*)(base + (long)row * 2048 + cq * 4);
        float m = v.x, s = 1.f;
        msmerge(m, s, v.y, 1.f);
        msmerge(m, s, v.z, 1.f);
        msmerge(m, s, v.w, 1.f);
        for (int o = 1; o < 16; o <<= 1) {
            float om = __shfl_xor(m, o, 64);
            float os = __shfl_xor(s, o, 64);
            msmerge(m, s, om, os);
        }
        if (cq == 0) {
            int idx = (b * 32 + blockIdx.x) * 2048 + m0 + row;
            rowm[idx] = m; rows_[idx] = s;
        }
        T[cq * 4 + 0][row] = f2bf(v.x);
        T[cq * 4 + 1][row] = f2bf(v.y);
        T[cq * 4 + 2][row] = f2bf(v.z);
        T[cq * 4 + 3][row] = f2bf(v.w);
    }
    __syncthreads();
#pragma unroll
    for (int p = 0; p < 4; ++p) {
        int rn = p * 16 + r16;
        float v0 = bf2f(T[rn][cq * 4 + 0]);
        float v1 = bf2f(T[rn][cq * 4 + 1]);
        float v2 = bf2f(T[rn][cq * 4 + 2]);
        float v3 = bf2f(T[rn][cq * 4 + 3]);
        uint2 o;
        o.x = (unsigned)T[rn][cq * 4 + 0] | ((unsigned)T[rn][cq * 4 + 1] << 16);
        o.y = (unsigned)T[rn][cq * 4 + 2] | ((unsigned)T[rn][cq * 4 + 3] << 16);
        *(uint2*)&At10[((long)b * 2048 + n0 + rn) * 2048 + m0 + cq * 4] = o;
        float m = v0, s = 1.f;
        msmerge(m, s, v1, 1.f);
        msmerge(m, s, v2, 1.f);
        msmerge(m, s, v3, 1.f);
        for (int o2 = 1; o2 < 16; o2 <<= 1) {
            float om = __shfl_xor(m, o2, 64);
            float os = __shfl_xor(s, o2, 64);
            msmerge(m, s, om, os);
        }
        if (cq == 0) {
            int idx = (b * 32 + blockIdx.y) * 2048 + n0 + rn;
            colm[idx] = m; cols_[idx] = s;
        }
    }
}

// combine nch chunk partials -> LSE per (b, n)
__global__ void k_statcomb(const float* __restrict__ pm, const float* __restrict__ ps,
                           int nch, float* __restrict__ out) {
    int idx = blockIdx.x * 256 + threadIdx.x;  // 8192
    int b = idx >> 11, n = idx & 2047;
    float mx = -3.4e38f;
    for (int c = 0; c < nch; ++c) mx = fmaxf(mx, pm[(b * nch + c) * 2048 + n]);
    float s = 0.f;
    for (int c = 0; c < nch; ++c) s += ps[(b * nch + c) * 2048 + n] * __expf(pm[(b * nch + c) * 2048 + n] - mx);
    out[idx] = mx + logf(s);
}

// ---------------- bf16 transpose of 8 slabs (2048,256)->(256,2048); dst slab = src^4 ----------------
__global__ void k_tr(const ushort_t* __restrict__ src, ushort_t* __restrict__ dst) {
    int z = blockIdx.z;
    int c0 = blockIdx.x * 64, r0 = blockIdx.y * 64;
    const ushort_t* s = src + (long)z * 524288;
    ushort_t* d = dst + (long)(z ^ 4) * 524288;
    __shared__ ushort_t T[64][68];
    int t = threadIdx.x;
    int ir = t >> 4, jc = t & 15;
#pragma unroll
    for (int p = 0; p < 4; ++p) {
        int row = p * 16 + ir;
        uint2 v = *(const uint2*)&s[(long)(r0 + row) * 256 + c0 + jc * 4];
        T[jc * 4 + 0][row] = (ushort_t)(v.x & 0xffff);
        T[jc * 4 + 1][row] = (ushort_t)(v.x >> 16);
        T[jc * 4 + 2][row] = (ushort_t)(v.y & 0xffff);
        T[jc * 4 + 3][row] = (ushort_t)(v.y >> 16);
    }
    __syncthreads();
#pragma unroll
    for (int p = 0; p < 4; ++p) {
        int crow = p * 16 + ir;
        uint2 o;
        o.x = (unsigned)T[crow][jc * 4 + 0] | ((unsigned)T[crow][jc * 4 + 1] << 16);
        o.y = (unsigned)T[crow][jc * 4 + 2] | ((unsigned)T[crow][jc * 4 + 3] << 16);
        *(uint2*)&d[(long)(c0 + crow) * 2048 + r0 + jc * 4] = o;
    }
}

// ---------------- gemm64: 64x64 tile, 4 waves 2x2 of 32x32 ----------------
template <class Epi>
__global__ __launch_bounds__(256, 4) void gemm64(const ushort_t* __restrict__ A, int lda,
                                                 const ushort_t* __restrict__ Bt, int ldb,
                                                 int K, Epi epi) {
    __shared__ ushort_t lA[8 * 66 * 8];
    __shared__ ushort_t lB[8 * 66 * 8];
    const int m0 = blockIdx.x * 64, n0 = blockIdx.y * 64;
    const int t = threadIdx.x;
    const int lane = t & 63, wave = t >> 6;
    const int wm = (wave & 1) * 32, wn = (wave >> 1) * 32;
    const int q = lane >> 4, lm = lane & 15;
    const int r0 = t >> 3, kc = t & 7;
    const int r1 = 32 + r0;
    const int4* pa0 = (const int4*)(A + (long)(m0 + r0) * lda + kc * 8);
    const int4* pa1 = (const int4*)(A + (long)(m0 + r1) * lda + kc * 8);
    const int4* pb0 = (const int4*)(Bt + (long)(n0 + r0) * ldb + kc * 8);
    const int4* pb1 = (const int4*)(Bt + (long)(n0 + r1) * ldb + kc * 8);
    f32x4 zero = {0.f, 0.f, 0.f, 0.f};
    f32x4 acc[2][2];
    acc[0][0] = zero; acc[0][1] = zero; acc[1][0] = zero; acc[1][1] = zero;
    int4 ra0 = pa0[0], ra1 = pa1[0], rb0 = pb0[0], rb1 = pb1[0];
    const int nkt = K >> 6;
    for (int kt = 0; kt < nkt; ++kt) {
        __syncthreads();
        *(int4*)&lA[(kc * 66 + r0) * 8] = ra0;
        *(int4*)&lA[(kc * 66 + r1) * 8] = ra1;
        *(int4*)&lB[(kc * 66 + r0) * 8] = rb0;
        *(int4*)&lB[(kc * 66 + r1) * 8] = rb1;
        __syncthreads();
        if (kt + 1 < nkt) {
            ra0 = pa0[(kt + 1) * 8]; ra1 = pa1[(kt + 1) * 8];
            rb0 = pb0[(kt + 1) * 8]; rb1 = pb1[(kt + 1) * 8];
        }
#pragma unroll
        for (int kk = 0; kk < 2; ++kk) {
            bf16x8 af[2], bfr[2];
#pragma unroll
            for (int mi = 0; mi < 2; ++mi)
                af[mi] = *(const bf16x8*)&lA[((kk * 4 + q) * 66 + wm + mi * 16 + lm) * 8];
#pragma unroll
            for (int ni = 0; ni < 2; ++ni)
                bfr[ni] = *(const bf16x8*)&lB[((kk * 4 + q) * 66 + wn + ni * 16 + lm) * 8];
#pragma unroll
            for (int mi = 0; mi < 2; ++mi)
#pragma unroll
                for (int ni = 0; ni < 2; ++ni)
                    acc[mi][ni] = __builtin_amdgcn_mfma_f32_16x16x32_bf16(af[mi], bfr[ni], acc[mi][ni], 0, 0, 0);
        }
    }
#pragma unroll
    for (int mi = 0; mi < 2; ++mi)
#pragma unroll
        for (int ni = 0; ni < 2; ++ni)
#pragma unroll
            for (int r2 = 0; r2 < 4; ++r2) {
                int row = m0 + wm + mi * 16 + q * 4 + r2;
                int col = n0 + wn + ni * 16 + lm;
                epi(row, col, acc[mi][ni][r2]);
            }
}

struct GeU {
    ushort_t* dst; const float* bias;
    __device__ void operator()(int r, int c, float v) const {
        dst[(long)r * 256 + c] = f2bf(v + bias[c]);
    }
};
struct GeH {
    float* dst; const float* bias;
    __device__ void operator()(int r, int c, float v) const {
        dst[(long)r * 512 + c] = v + bias[c];
    }
};
struct GeD {
    ushort_t* dst; const float* bias; const float* x0; const float* x1;
    __device__ void operator()(int r, int c, float v) const {
        float rx = (r < 8192) ? x0[(long)r * 256 + c] : x1[(long)(r - 8192) * 256 + c];
        dst[(long)r * 256 + c] = f2bf(v + bias[c] + rx);
    }
};
struct GeMd {
    ushort_t* dst; const float* bias;
    __device__ void operator()(int r, int c, float v) const {
        dst[(long)r * 256 + c] = f2bf((v + bias[c]) * 0.25f);
    }
};

// ---------------- fused m-GEMM: softmax(adj) @ u -> cat bf16, no split-K ----------------
// grid (64 mtiles of 32 rows, 1, 8): z<4 -> m0 (fp32 adj + rlse), z>=4 -> m1 (bf16 adjT + clse)
__global__ __launch_bounds__(256, 2) void gemm_madj(
    const float* __restrict__ adj, const ushort_t* __restrict__ At10,
    const ushort_t* __restrict__ ut, const float* __restrict__ rlse,
    const float* __restrict__ clse, ushort_t* __restrict__ cat) {
    __shared__ ushort_t lA[8 * 34 * 8];
    __shared__ ushort_t lB[8 * 258 * 8];  // also reused as 32x264 bf16 output stage
    const int z = blockIdx.z, b = z & 3, side = z >> 2;
    const int m0 = blockIdx.x * 32;
    const int t = threadIdx.x;
    const int lane = t & 63, wave = t >> 6;
    const int q = lane >> 4, lm = lane & 15;
    const float* rs = (side == 0 ? rlse : clse) + b * 2048 + m0;
    const int bd = t >> 3, bkc = t & 7;
    const int4* pb[8];
#pragma unroll
    for (int i = 0; i < 8; ++i)
        pb[i] = (const int4*)(ut + (long)z * 524288 + (long)(i * 32 + bd) * 2048 + bkc * 8);
    const int ar = t >> 4, ac4 = t & 15;
    const float* paf[2];
    float rlf[2];
#pragma unroll
    for (int i = 0; i < 2; ++i) {
        paf[i] = adj + ((long)(b * 2048 + m0 + i * 16 + ar)) * 2048 + ac4 * 4;
        rlf[i] = rs[i * 16 + ar];
    }
    const int tr0 = t >> 3, tkc = t & 7;
    const int4* pat = (const int4*)(At10 + ((long)(b * 2048 + m0 + tr0)) * 2048 + tkc * 8);
    float rlt = rs[tr0];

    f32x4 zero = {0.f, 0.f, 0.f, 0.f};
    f32x4 acc[2][4];
#pragma unroll
    for (int mi = 0; mi < 2; ++mi)
#pragma unroll
        for (int ni = 0; ni < 4; ++ni) acc[mi][ni] = zero;

    int4 rb[8];
#pragma unroll
    for (int i = 0; i < 8; ++i) rb[i] = pb[i][0];
    float4 raf[2];
    int4 rat;
    if (side == 0) {
#pragma unroll
        for (int i = 0; i < 2; ++i) raf[i] = *(const float4*)(paf[i]);
    } else {
        rat = pat[0];
    }
    for (int kt = 0; kt < 32; ++kt) {
        __syncthreads();
#pragma unroll
        for (int i = 0; i < 8; ++i) *(int4*)&lB[(bkc * 258 + i * 32 + bd) * 8] = rb[i];
        if (side == 0) {
#pragma unroll
            for (int i = 0; i < 2; ++i) {
                float4 v = raf[i];
                float rl = rlf[i];
                uint2 o;
                o.x = (unsigned)f2bf(__expf(v.x - rl)) | ((unsigned)f2bf(__expf(v.y - rl)) << 16);
                o.y = (unsigned)f2bf(__expf(v.z - rl)) | ((unsigned)f2bf(__expf(v.w - rl)) << 16);
                *(uint2*)&lA[((ac4 >> 1) * 34 + i * 16 + ar) * 8 + (ac4 & 1) * 4] = o;
            }
        } else {
            int4 w = rat;
            float rl = rlt;
            unsigned u[4] = {(unsigned)w.x, (unsigned)w.y, (unsigned)w.z, (unsigned)w.w};
            uint2 o0, o1;
            o0.x = (unsigned)f2bf(__expf(bf2f((ushort_t)(u[0] & 0xffff)) - rl)) |
                   ((unsigned)f2bf(__expf(bf2f((ushort_t)(u[0] >> 16)) - rl)) << 16);
            o0.y = (unsigned)f2bf(__expf(bf2f((ushort_t)(u[1] & 0xffff)) - rl)) |
                   ((unsigned)f2bf(__expf(bf2f((ushort_t)(u[1] >> 16)) - rl)) << 16);
            o1.x = (unsigned)f2bf(__expf(bf2f((ushort_t)(u[2] & 0xffff)) - rl)) |
                   ((unsigned)f2bf(__expf(bf2f((ushort_t)(u[2] >> 16)) - rl)) << 16);
            o1.y = (unsigned)f2bf(__expf(bf2f((ushort_t)(u[3] & 0xffff)) - rl)) |
                   ((unsigned)f2bf(__expf(bf2f((ushort_t)(u[3] >> 16)) - rl)) << 16);
            *(uint2*)&lA[(tkc * 34 + tr0) * 8] = o0;
            *(uint2*)&lA[(tkc * 34 + tr0) * 8 + 4] = o1;
        }
        __syncthreads();
        if (kt + 1 < 32) {
#pragma unroll
            for (int i = 0; i < 8; ++i) rb[i] = pb[i][(kt + 1) * 8];
            if (side == 0) {
#pragma unroll
                for (int i = 0; i < 2; ++i) raf[i] = *(const float4*)(paf[i] + (kt + 1) * 64);
            } else {
                rat = pat[(kt + 1) * 8];
            }
        }
#pragma unroll
        for (int kk = 0; kk < 2; ++kk) {
            bf16x8 af[2], bfr[4];
#pragma unroll
            for (int mi = 0; mi < 2; ++mi)
                af[mi] = *(const bf16x8*)&lA[((kk * 4 + q) * 34 + mi * 16 + lm) * 8];
#pragma unroll
            for (int ni = 0; ni < 4; ++ni)
                bfr[ni] = *(const bf16x8*)&lB[((kk * 4 + q) * 258 + wave * 64 + ni * 16 + lm) * 8];
#pragma unroll
            for (int mi = 0; mi < 2; ++mi)
#pragma unroll
                for (int ni = 0; ni < 4; ++ni)
                    acc[mi][ni] = __builtin_amdgcn_mfma_f32_16x16x32_bf16(af[mi], bfr[ni], acc[mi][ni], 0, 0, 0);
        }
    }
    // epilogue: stage 32x256 bf16 in LDS (stride 264), then coalesced 16B stores
    __syncthreads();
    ushort_t* stg = lB;
#pragma unroll
    for (int mi = 0; mi < 2; ++mi)
#pragma unroll
        for (int ni = 0; ni < 4; ++ni)
#pragma unroll
            for (int r2 = 0; r2 < 4; ++r2) {
                int row = mi * 16 + q * 4 + r2;
                int col = wave * 64 + ni * 16 + lm;
                stg[row * 264 + col] = f2bf(acc[mi][ni][r2]);
            }
    __syncthreads();
    {
        int row = t >> 3, ch = t & 7;
        long g = ((long)(z * 2048 + m0 + row)) * 512 + 256 + ch * 32;
#pragma unroll
        for (int j = 0; j < 4; ++j)
            *(int4*)&cat[g + j * 8] = *(const int4*)&stg[row * 264 + ch * 32 + j * 8];
    }
}

// ---------------- sim GEMM: md0 @ md1^T (128x128 tile) + fused LSE partials ----------------
// grid (16 mtiles, 16 ntiles, 4 b)
__global__ __launch_bounds__(256, 2) void gemm_sim(
    const ushort_t* __restrict__ mdb, ushort_t* __restrict__ simb,
    float* __restrict__ rpm, float* __restrict__ rps,
    float* __restrict__ cpm, float* __restrict__ cps) {
    __shared__ ushort_t lA[8 * 130 * 8];
    __shared__ ushort_t lB[8 * 130 * 8];
    __shared__ ushort_t stg[128 * 136];
    __shared__ float rsm[128][2], rss[128][2], csm[128][2], css[128][2];
    const int b = blockIdx.z;
    const int m0 = blockIdx.x * 128, n0 = blockIdx.y * 128;
    const ushort_t* A = mdb + (long)b * 524288;
    const ushort_t* Bt = mdb + (long)(4 + b) * 524288;
    const int t = threadIdx.x;
    const int lane = t & 63, wave = t >> 6;
    const int wm = (wave & 1) * 64, wn = (wave >> 1) * 64;
    const int q = lane >> 4, lm = lane & 15;
    const int4* pa[4];
    const int4* pb[4];
    int arow[4], akc[4];
#pragma unroll
    for (int i = 0; i < 4; ++i) {
        int c = i * 256 + t;
        arow[i] = c >> 3;
        akc[i] = c & 7;
        pa[i] = (const int4*)(A + (long)(m0 + arow[i]) * 256 + akc[i] * 8);
        pb[i] = (const int4*)(Bt + (long)(n0 + arow[i]) * 256 + akc[i] * 8);
    }
    f32x4 zero = {0.f, 0.f, 0.f, 0.f};
    f32x4 acc[4][4];
#pragma unroll
    for (int mi = 0; mi < 4; ++mi)
#pragma unroll
        for (int ni = 0; ni < 4; ++ni) acc[mi][ni] = zero;
    int4 ra[4], rb[4];
#pragma unroll
    for (int i = 0; i < 4; ++i) { ra[i] = pa[i][0]; rb[i] = pb[i][0]; }
    for (int kt = 0; kt < 4; ++kt) {
        __syncthreads();
#pragma unroll
        for (int i = 0; i < 4; ++i) {
            *(int4*)&lA[(akc[i] * 130 + arow[i]) * 8] = ra[i];
            *(int4*)&lB[(akc[i] * 130 + arow[i]) * 8] = rb[i];
        }
        __syncthreads();
        if (kt + 1 < 4) {
#pragma unroll
            for (int i = 0; i < 4; ++i) { ra[i] = pa[i][(kt + 1) * 8]; rb[i] = pb[i][(kt + 1) * 8]; }
        }
#pragma unroll
        for (int kk = 0; kk < 2; ++kk) {
            bf16x8 af[4], bfr[4];
#pragma unroll
            for (int mi = 0; mi < 4; ++mi)
                af[mi] = *(const bf16x8*)&lA[((kk * 4 + q) * 130 + wm + mi * 16 + lm) * 8];
#pragma unroll
            for (int ni = 0; ni < 4; ++ni)
                bfr[ni] = *(const bf16x8*)&lB[((kk * 4 + q) * 130 + wn + ni * 16 + lm) * 8];
#pragma unroll
            for (int mi = 0; mi < 4; ++mi)
#pragma unroll
                for (int ni = 0; ni < 4; ++ni)
                    acc[mi][ni] = __builtin_amdgcn_mfma_f32_16x16x32_bf16(af[mi], bfr[ni], acc[mi][ni], 0, 0, 0);
        }
    }
    // row (max,sumexp) partials over this block's 128 cols
#pragma unroll
    for (int mi = 0; mi < 4; ++mi)
#pragma unroll
        for (int r2 = 0; r2 < 4; ++r2) {
            float mx = acc[mi][0][r2], sm = 1.f;
#pragma unroll
            for (int ni = 1; ni < 4; ++ni) msmerge(mx, sm, acc[mi][ni][r2], 1.f);
#pragma unroll
            for (int o = 1; o < 16; o <<= 1) {
                float om = __shfl_xor(mx, o, 64);
                float os = __shfl_xor(sm, o, 64);
                msmerge(mx, sm, om, os);
            }
            if (lm == 0) {
                int row = wm + mi * 16 + q * 4 + r2;
                rsm[row][wn >> 6] = mx; rss[row][wn >> 6] = sm;
            }
        }
    // col (max,sumexp) partials over this block's 128 rows
#pragma unroll
    for (int ni = 0; ni < 4; ++ni) {
        float mx = acc[0][ni][0], sm = 1.f;
#pragma unroll
        for (int mi = 0; mi < 4; ++mi)
#pragma unroll
            for (int r2 = 0; r2 < 4; ++r2) {
                if (mi == 0 && r2 == 0) continue;
                msmerge(mx, sm, acc[mi][ni][r2], 1.f);
            }
#pragma unroll
        for (int o = 16; o < 64; o <<= 1) {
            float om = __shfl_xor(mx, o, 64);
            float os = __shfl_xor(sm, o, 64);
            msmerge(mx, sm, om, os);
        }
        if (q == 0) {
            int col = wn + ni * 16 + lm;
            csm[col][wm >> 6] = mx; css[col][wm >> 6] = sm;
        }
    }
    // stage bf16 output
#pragma unroll
    for (int mi = 0; mi < 4; ++mi)
#pragma unroll
        for (int ni = 0; ni < 4; ++ni)
#pragma unroll
            for (int r2 = 0; r2 < 4; ++r2)
                stg[(wm + mi * 16 + q * 4 + r2) * 136 + wn + ni * 16 + lm] = f2bf(acc[mi][ni][r2]);
    __syncthreads();
    if (t < 128) {
        float m = rsm[t][0], s = rss[t][0];
        msmerge(m, s, rsm[t][1], rss[t][1]);
        int idx = (b * 16 + blockIdx.y) * 2048 + m0 + t;
        rpm[idx] = m; rps[idx] = s;
    } else {
        int c = t - 128;
        float m = csm[c][0], s = css[c][0];
        msmerge(m, s, csm[c][1], css[c][1]);
        int idx = (b * 16 + blockIdx.x) * 2048 + n0 + c;
        cpm[idx] = m; cps[idx] = s;
    }
    {
        int row = t >> 1, half = t & 1;
        long g = (long)b * 4194304 + (long)(m0 + row) * 2048 + n0 + half * 64;
#pragma unroll
        for (int j = 0; j < 8; ++j)
            *(int4*)&simb[g + j * 8] = *(const int4*)&stg[row * 136 + half * 64 + j * 8];
    }
}

// ---------------- LN + GELU (rows of 512) ----------------
__global__ void k_ln(const float* __restrict__ h, const float* __restrict__ lng,
                     const float* __restrict__ lnb, ushort_t* __restrict__ out) {
    int row = blockIdx.x;
    int t = threadIdx.x;
    const float* p = h + (long)row * 512;
    float a = p[t], c = p[t + 256];
    float s = wredsum(a + c);
    __shared__ float sh[4];
    if ((t & 63) == 0) sh[t >> 6] = s;
    __syncthreads();
    float mean = (sh[0] + sh[1] + sh[2] + sh[3]) * (1.f / 512.f);
    float da = a - mean, dc = c - mean;
    float s2 = wredsum(da * da + dc * dc);
    __shared__ float sh2[4];
    if ((t & 63) == 0) sh2[t >> 6] = s2;
    __syncthreads();
    float var = (sh2[0] + sh2[1] + sh2[2] + sh2[3]) * (1.f / 512.f);
    float inv = rsqrtf(var + 1e-5f);
    float x1 = da * inv * lng[t] + lnb[t];
    float x2 = dc * inv * lng[t + 256] + lnb[t + 256];
    float g1 = 0.5f * x1 * (1.f + erff(x1 * 0.70710678118654752f));
    float g2 = 0.5f * x2 * (1.f + erff(x2 * 0.70710678118654752f));
    out[(long)row * 512 + t] = f2bf(g1);
    out[(long)row * 512 + t + 256] = f2bf(g2);
}

// ---------------- z = d @ Wz + bz -> log_sigmoid(+-z); 16384 merged rows ----------------
__global__ void k_z(const ushort_t* __restrict__ dmat, const float* __restrict__ Wz,
                    const float* __restrict__ bzp, float* __restrict__ lszp,
                    float* __restrict__ lszn) {
    int row = blockIdx.x * 4 + (threadIdx.x >> 6);
    int l = threadIdx.x & 63;
    const ushort_t* p = dmat + (long)row * 256 + l * 4;
    float4 w = *(const float4*)(Wz + l * 4);
    float s = bf2f(p[0]) * w.x + bf2f(p[1]) * w.y + bf2f(p[2]) * w.z + bf2f(p[3]) * w.w;
    s = wredsum(s);
    if (l == 0) {
        float z = s + bzp[0];
        lszp[row] = logsig(z);
        lszn[row] = logsig(-z);
    }
}

// ---------------- fused: transform simb -> scores, row max/argmax, col-argmax partials ----------------
// grid 512: b = blk>>7, chunk of 16 rows = blk&127
__global__ void k_scores2(const ushort_t* __restrict__ simb, float* __restrict__ scores,
                          const float* __restrict__ rowLSE, const float* __restrict__ colLSE,
                          const float* __restrict__ lszp, const float* __restrict__ lszn,
                          float* __restrict__ rmax, int* __restrict__ ridx,
                          float* __restrict__ pcv, int* __restrict__ pci) {
    int blk = blockIdx.x;
    int b = blk >> 7, ch = blk & 127;
    int t = threadIdx.x;
    int lane = t & 63, wave = t >> 6;
    int n0 = t * 8;
    const float* cl = colLSE + b * 2048;
    const float* l1p = lszp + 8192 + b * 2048;
    float clv[8], l1v[8];
#pragma unroll
    for (int j = 0; j < 8; ++j) { clv[j] = cl[n0 + j]; l1v[j] = l1p[n0 + j]; }
    float cbv[8];
    int cbi[8];
#pragma unroll
    for (int j = 0; j < 8; ++j) { cbv[j] = -3.4e38f; cbi[j] = 0; }
    __shared__ float rv[16][4];
    __shared__ int ri[16][4];
    for (int r = 0; r < 16; ++r) {
        int m = ch * 16 + r;
        int gm = b * 2048 + m;
        float rl = rowLSE[gm], l0 = lszp[gm];
        float base = l0 - rl;
        int4 w = *(const int4*)&simb[(long)b * 4194304 + (long)m * 2048 + n0];
        unsigned u[4] = {(unsigned)w.x, (unsigned)w.y, (unsigned)w.z, (unsigned)w.w};
        float* dst = scores + (long)b * 4198401 + (long)m * 2049 + n0;
        float bv = -3.4e38f;
        int bi = 0;
#pragma unroll
        for (int i = 0; i < 4; ++i) {
#pragma unroll
            for (int h = 0; h < 2; ++h) {
                int j = i * 2 + h;
                float sv = bf2f((ushort_t)(h ? (u[i] >> 16) : (u[i] & 0xffff)));
                float tv = 2.f * sv + base;
                float v = tv - clv[j] + l1v[j];
                dst[j] = v;
                if (v > bv) { bv = v; bi = n0 + j; }
                if (tv > cbv[j]) { cbv[j] = tv; cbi[j] = m; }
            }
        }
        for (int o = 32; o; o >>= 1) {
            float ov = __shfl_xor(bv, o, 64);
            int oi = __shfl_xor(bi, o, 64);
            if (ov > bv || (ov == bv && oi < bi)) { bv = ov; bi = oi; }
        }
        if (lane == 0) { rv[r][wave] = bv; ri[r][wave] = bi; }
    }
    __syncthreads();
    if (t < 16) {
        float bv = rv[t][0];
        int bi = ri[t][0];
        for (int w2 = 1; w2 < 4; ++w2)
            if (rv[t][w2] > bv || (rv[t][w2] == bv && ri[t][w2] < bi)) { bv = rv[t][w2]; bi = ri[t][w2]; }
        int gm = b * 2048 + ch * 16 + t;
        rmax[gm] = bv;
        ridx[gm] = bi;
        scores[(long)b * 4198401 + (long)(ch * 16 + t) * 2049 + 2048] = lszn[gm];
    }
    long pidx = (long)(b * 128 + ch) * 2048 + n0;
#pragma unroll
    for (int j = 0; j < 8; ++j) { pcv[pidx + j] = cbv[j]; pci[pidx + j] = cbi[j]; }
}

// ---------------- combine col argmax chunks, write border row + corner ----------------
__global__ void k_colmaxB(const float* __restrict__ pcv, const int* __restrict__ pci,
                          const float* __restrict__ lszn, float* __restrict__ scores,
                          int* __restrict__ cidx) {
    int idx = blockIdx.x * 256 + threadIdx.x;  // 8192
    int b = idx >> 11, n = idx & 2047;
    float bv = -3.4e38f;
    int bi = 0;
    for (int c = 0; c < 128; ++c) {
        float v = pcv[(long)(b * 128 + c) * 2048 + n];
        int i = pci[(long)(b * 128 + c) * 2048 + n];
        if (v > bv || (v == bv && i < bi)) { bv = v; bi = i; }
    }
    cidx[idx] = bi;
    scores[(long)b * 4198401 + 2048L * 2049 + n] = lszn[8192 + idx];
    if (n == 0) scores[(long)b * 4198401 + 2048L * 2049 + 2048] = 0.f;
}

__global__ void k_match0(const int* __restrict__ ridx, const int* __restrict__ cidx,
                         const float* __restrict__ rmax, float* __restrict__ m0out,
                         float* __restrict__ ms0out, float* __restrict__ ms0ws,
                         int* __restrict__ v0ws) {
    int idx = blockIdx.x * 256 + threadIdx.x;
    int b = idx >> 11, m = idx & 2047;
    int j = ridx[idx];
    bool mutual = (cidx[b * 2048 + j] == m);
    float e = mutual ? expf(rmax[idx]) : 0.f;
    bool valid = mutual && (e > 0.1f);
    m0out[idx] = valid ? (float)j : -1.f;
    ms0out[idx] = e;
    ms0ws[idx] = e;
    v0ws[idx] = valid ? 1 : 0;
}

__global__ void k_match1(const int* __restrict__ cidx, const int* __restrict__ ridx,
                         const float* __restrict__ ms0ws, const int* __restrict__ v0ws,
                         float* __restrict__ m1out, float* __restrict__ ms1out) {
    int idx = blockIdx.x * 256 + threadIdx.x;
    int b = idx >> 11, n = idx & 2047;
    int j = cidx[idx];
    bool mutual = (ridx[b * 2048 + j] == n);
    float ms1 = mutual ? ms0ws[b * 2048 + j] : 0.f;
    bool valid = mutual && (v0ws[b * 2048 + j] != 0);
    m1out[idx] = valid ? (float)j : -1.f;
    ms1out[idx] = ms1;
}

extern "C" void kernel_launch(void* const* d_in, const int* in_sizes, int n_in,
                              void* d_out, int out_size, void* d_ws, size_t ws_size,
                              hipStream_t stream) {
    (void)in_sizes; (void)n_in; (void)out_size; (void)ws_size;
    const float* x0  = (const float*)d_in[0];
    const float* x1  = (const float*)d_in[1];
    const float* adj = (const float*)d_in[2];
    const float* Wv  = (const float*)d_in[3];
    const float* bv  = (const float*)d_in[4];
    const float* Wo  = (const float*)d_in[5];
    const float* bo  = (const float*)d_in[6];
    const float* Wf1 = (const float*)d_in[7];
    const float* bf1 = (const float*)d_in[8];
    const float* lng = (const float*)d_in[9];
    const float* lnb = (const float*)d_in[10];
    const float* Wf2 = (const float*)d_in[11];
    const float* bf2 = (const float*)d_in[12];
    const float* Wfp = (const float*)d_in[13];
    const float* bfp = (const float*)d_in[14];
    const float* Wz  = (const float*)d_in[15];
    const float* bz  = (const float*)d_in[16];

    float* out = (float*)d_out;
    float* scores  = out;
    float* out_m0  = out + 16793604;
    float* out_m1  = out_m0 + 8192;
    float* out_ms0 = out_m1 + 8192;
    float* out_ms1 = out_ms0 + 8192;

    char* base = (char*)d_ws;
    // [0, 33.5M): At10 raw bf16 (prep->madj), then hbuf fp32 (h-gemm->ln)
    ushort_t* At10 = (ushort_t*)base;
    float*    hbuf = (float*)base;
    // [33.5M, 67M): simb bf16 (sim-gemm -> scores2)
    ushort_t* simb = (ushort_t*)(base + 33554432);
    size_t off = 67108864;
    auto alloc = [&](size_t sz) { char* p = base + off; off += (sz + 255) & ~(size_t)255; return p; };
    ushort_t* cat  = (ushort_t*)alloc(16777216);   // 16384x512 bf16
    ushort_t* ubuf = (ushort_t*)alloc(8388608);    // 16384x256 bf16 ; later pcv (4MB)
    ushort_t* ut   = (ushort_t*)alloc(8388608);    // 8 slabs 256x2048 ; later pci (4MB)
    ushort_t* gbuf = (ushort_t*)alloc(16777216);   // 16384x512 bf16
    ushort_t* dbuf = (ushort_t*)alloc(8388608);    // 16384x256 bf16
    ushort_t* mdb  = (ushort_t*)alloc(8388608);    // 16384x256 bf16
    ushort_t* Wovb = (ushort_t*)alloc(131072);
    ushort_t* Wf1b = (ushort_t*)alloc(524288);
    ushort_t* Wf2b = (ushort_t*)alloc(262144);
    ushort_t* Wfpb = (ushort_t*)alloc(131072);
    float* bvo     = (float*)alloc(1024);
    float* rowm    = (float*)alloc(1048576);
    float* rows_   = (float*)alloc(1048576);
    float* colm    = (float*)alloc(1048576);
    float* cols_   = (float*)alloc(1048576);
    float* rlse    = (float*)alloc(32768);
    float* clse    = (float*)alloc(32768);
    float* rpm     = (float*)alloc(524288);
    float* rps     = (float*)alloc(524288);
    float* cpm     = (float*)alloc(524288);
    float* cps     = (float*)alloc(524288);
    float* rowLSE  = (float*)alloc(32768);
    float* colLSE  = (float*)alloc(32768);
    float* rmax    = (float*)alloc(32768);
    int*   ridx    = (int*)alloc(32768);
    int*   cidx    = (int*)alloc(32768);
    float* lszp    = (float*)alloc(65536);
    float* lszn    = (float*)alloc(65536);
    float* ms0ws   = (float*)alloc(32768);
    int*   v0ws    = (int*)alloc(32768);
    float* pcv = (float*)ubuf;   // overlay: ubuf dead after k_tr
    int*   pci = (int*)ut;       // overlay: ut dead after gemm_madj

    // ---- weight prep + casts ----
    k_wov<<<256, 256, 0, stream>>>(Wo, Wv, bv, bo, Wovb, bvo);
    k_cast_flat<<<1024, 256, 0, stream>>>(Wf1, Wf1b, 262144);
    k_cast_flat<<<512, 256, 0, stream>>>(Wf2, Wf2b, 131072);
    k_cast_flat<<<256, 256, 0, stream>>>(Wfp, Wfpb, 65536);
    k_cast_x<<<8192, 256, 0, stream>>>(x0, cat);
    k_cast_x<<<8192, 256, 0, stream>>>(x1, cat + 8192L * 512);

    // ---- adjacency: raw transpose + fused LSE partials ----
    k_prep<<<dim3(32, 32, 4), 256, 0, stream>>>(adj, At10, rowm, rows_, colm, cols_);
    k_statcomb<<<32, 256, 0, stream>>>(rowm, rows_, 32, rlse);
    k_statcomb<<<32, 256, 0, stream>>>(colm, cols_, 32, clse);

    // ---- u = x @ Wov.T + bvo, then transpose slab-swapped ----
    gemm64<<<dim3(256, 4), 256, 0, stream>>>(cat, 512, Wovb, 256, 256, GeU{ubuf, bvo});
    k_tr<<<dim3(4, 32, 8), 256, 0, stream>>>(ubuf, ut);

    // ---- fused m = softmax(adj) @ u -> cat[...,256:512], no split-K ----
    gemm_madj<<<dim3(64, 1, 8), 256, 0, stream>>>(adj, At10, ut, rlse, clse, cat);

    // ---- h = cat @ Wf1.T + bf1 ----
    gemm64<<<dim3(256, 8), 256, 0, stream>>>(cat, 512, Wf1b, 512, 512, GeH{hbuf, bf1});
    k_ln<<<16384, 256, 0, stream>>>(hbuf, lng, lnb, gbuf);

    // ---- d = x + g @ Wf2.T + bf2 ----
    gemm64<<<dim3(256, 4), 256, 0, stream>>>(gbuf, 512, Wf2b, 512, 512, GeD{dbuf, bf2, x0, x1});

    // ---- z / log_sigmoid ----
    k_z<<<4096, 256, 0, stream>>>(dbuf, Wz, bz, lszp, lszn);

    // ---- md = (d @ Wfp.T + bfp)/4 ----
    gemm64<<<dim3(256, 4), 256, 0, stream>>>(dbuf, 256, Wfpb, 256, 256, GeMd{mdb, bfp});

    // ---- sim = md0 @ md1^T -> simb bf16, with fused row/col LSE partials ----
    gemm_sim<<<dim3(16, 16, 4), 256, 0, stream>>>(mdb, simb, rpm, rps, cpm, cps);
    k_statcomb<<<32, 256, 0, stream>>>(rpm, rps, 16, rowLSE);
    k_statcomb<<<32, 256, 0, stream>>>(cpm, cps, 16, colLSE);

    // ---- transform + row argmax + col-argmax partials ----
    k_scores2<<<512, 256, 0, stream>>>(simb, scores, rowLSE, colLSE, lszp, lszn,
                                       rmax, ridx, pcv, pci);
    k_colmaxB<<<32, 256, 0, stream>>>(pcv, pci, lszn, scores, cidx);

    // ---- mutual matching ----
    k_match0<<<32, 256, 0, stream>>>(ridx, cidx, rmax, out_m0, out_ms0, ms0ws, v0ws);
    k_match1<<<32, 256, 0, stream>>>(cidx, ridx, ms0ws, v0ws, out_m1, out_ms1);
}

// Round 6
// 577.851 us; speedup vs baseline: 1.1045x; 1.1045x over previous
//
#include <hip/hip_runtime.h>

typedef unsigned short ushort_t;
typedef __bf16 bf16x8 __attribute__((ext_vector_type(8)));
typedef float f32x4 __attribute__((ext_vector_type(4)));

__device__ __forceinline__ ushort_t f2bf(float f) {
    unsigned int u = __float_as_uint(f);
    unsigned int r = (u + 0x7fffu + ((u >> 16) & 1u)) >> 16;
    return (ushort_t)r;
}
__device__ __forceinline__ float bf2f(ushort_t u) {
    return __uint_as_float(((unsigned int)u) << 16);
}
__device__ __forceinline__ float wredsum(float v) {
    for (int o = 32; o; o >>= 1) v += __shfl_xor(v, o, 64);
    return v;
}
__device__ __forceinline__ float logsig(float z) {
    return (z >= 0.f) ? -log1pf(expf(-z)) : (z - log1pf(expf(z)));
}
__device__ __forceinline__ void msmerge(float& m, float& s, float om, float os) {
    float M = fmaxf(m, om);
    s = s * __expf(m - M) + os * __expf(om - M);
    m = M;
}
// async global->LDS copy, 16B per lane; LDS dest = wave-uniform base + lane*16
__device__ __forceinline__ void gload_lds16(const void* g, void* l) {
    __builtin_amdgcn_global_load_lds(
        (const __attribute__((address_space(1))) unsigned int*)g,
        (__attribute__((address_space(3))) unsigned int*)l, 16, 0, 0);
}

// ---------------- weight prep: Wov = Wo @ Wv, bvo = Wo@bv + bo ----------------
__global__ void k_wov(const float* __restrict__ Wo, const float* __restrict__ Wv,
                      const float* __restrict__ bvv, const float* __restrict__ bo,
                      ushort_t* __restrict__ Wovb, float* __restrict__ bvo) {
    int o = blockIdx.x, k = threadIdx.x;
    float s = 0.f;
    for (int j = 0; j < 256; ++j) s += Wo[o * 256 + j] * Wv[j * 256 + k];
    Wovb[o * 256 + k] = f2bf(s);
    float pb = Wo[o * 256 + k] * bvv[k];
    pb = wredsum(pb);
    __shared__ float sh[4];
    if ((k & 63) == 0) sh[k >> 6] = pb;
    __syncthreads();
    if (k == 0) bvo[o] = sh[0] + sh[1] + sh[2] + sh[3] + bo[o];
}

__global__ void k_cast_flat(const float* __restrict__ src, ushort_t* __restrict__ dst, int n) {
    int i = blockIdx.x * 256 + threadIdx.x;
    if (i < n) dst[i] = f2bf(src[i]);
}

// x (R,256) fp32 -> cat (R,512) bf16 at cols [0,256)
__global__ void k_cast_x(const float* __restrict__ src, ushort_t* __restrict__ dst) {
    long i = (long)blockIdx.x * 256 + threadIdx.x;
    long r = i >> 8;
    int c = (int)(i & 255);
    dst[r * 512 + c] = f2bf(src[i]);
}

// ---------------- fused adj pass: raw-transpose bf16 + row/col LSE partials ----------------
__global__ void k_prep(const float* __restrict__ adj, ushort_t* __restrict__ At10,
                       float* __restrict__ rowm, float* __restrict__ rows_,
                       float* __restrict__ colm, float* __restrict__ cols_) {
    int b = blockIdx.z;
    int n0 = blockIdx.x * 64, m0 = blockIdx.y * 64;
    __shared__ ushort_t T[64][72];
    int t = threadIdx.x;
    int r16 = t >> 4, cq = t & 15;
    const float* base = adj + ((long)b * 2048 + m0) * 2048 + n0;
#pragma unroll
    for (int p = 0; p < 4; ++p) {
        int row = p * 16 + r16;
        float4 v = *(const float4*)(base + (long)row * 2048 + cq * 4);
        float m = v.x, s = 1.f;
        msmerge(m, s, v.y, 1.f);
        msmerge(m, s, v.z, 1.f);
        msmerge(m, s, v.w, 1.f);
        for (int o = 1; o < 16; o <<= 1) {
            float om = __shfl_xor(m, o, 64);
            float os = __shfl_xor(s, o, 64);
            msmerge(m, s, om, os);
        }
        if (cq == 0) {
            int idx = (b * 32 + blockIdx.x) * 2048 + m0 + row;
            rowm[idx] = m; rows_[idx] = s;
        }
        T[cq * 4 + 0][row] = f2bf(v.x);
        T[cq * 4 + 1][row] = f2bf(v.y);
        T[cq * 4 + 2][row] = f2bf(v.z);
        T[cq * 4 + 3][row] = f2bf(v.w);
    }
    __syncthreads();
#pragma unroll
    for (int p = 0; p < 4; ++p) {
        int rn = p * 16 + r16;
        float v0 = bf2f(T[rn][cq * 4 + 0]);
        float v1 = bf2f(T[rn][cq * 4 + 1]);
        float v2 = bf2f(T[rn][cq * 4 + 2]);
        float v3 = bf2f(T[rn][cq * 4 + 3]);
        uint2 o;
        o.x = (unsigned)T[rn][cq * 4 + 0] | ((unsigned)T[rn][cq * 4 + 1] << 16);
        o.y = (unsigned)T[rn][cq * 4 + 2] | ((unsigned)T[rn][cq * 4 + 3] << 16);
        *(uint2*)&At10[((long)b * 2048 + n0 + rn) * 2048 + m0 + cq * 4] = o;
        float m = v0, s = 1.f;
        msmerge(m, s, v1, 1.f);
        msmerge(m, s, v2, 1.f);
        msmerge(m, s, v3, 1.f);
        for (int o2 = 1; o2 < 16; o2 <<= 1) {
            float om = __shfl_xor(m, o2, 64);
            float os = __shfl_xor(s, o2, 64);
            msmerge(m, s, om, os);
        }
        if (cq == 0) {
            int idx = (b * 32 + blockIdx.y) * 2048 + n0 + rn;
            colm[idx] = m; cols_[idx] = s;
        }
    }
}

// combine nch chunk partials -> LSE per (b, n)
__global__ void k_statcomb(const float* __restrict__ pm, const float* __restrict__ ps,
                           int nch, float* __restrict__ out) {
    int idx = blockIdx.x * 256 + threadIdx.x;  // 8192
    int b = idx >> 11, n = idx & 2047;
    float mx = -3.4e38f;
    for (int c = 0; c < nch; ++c) mx = fmaxf(mx, pm[(b * nch + c) * 2048 + n]);
    float s = 0.f;
    for (int c = 0; c < nch; ++c) s += ps[(b * nch + c) * 2048 + n] * __expf(pm[(b * nch + c) * 2048 + n] - mx);
    out[idx] = mx + logf(s);
}

// ---------------- bf16 transpose of 8 slabs (2048,256)->(256,2048); dst slab = src^4 ----------------
__global__ void k_tr(const ushort_t* __restrict__ src, ushort_t* __restrict__ dst) {
    int z = blockIdx.z;
    int c0 = blockIdx.x * 64, r0 = blockIdx.y * 64;
    const ushort_t* s = src + (long)z * 524288;
    ushort_t* d = dst + (long)(z ^ 4) * 524288;
    __shared__ ushort_t T[64][68];
    int t = threadIdx.x;
    int ir = t >> 4, jc = t & 15;
#pragma unroll
    for (int p = 0; p < 4; ++p) {
        int row = p * 16 + ir;
        uint2 v = *(const uint2*)&s[(long)(r0 + row) * 256 + c0 + jc * 4];
        T[jc * 4 + 0][row] = (ushort_t)(v.x & 0xffff);
        T[jc * 4 + 1][row] = (ushort_t)(v.x >> 16);
        T[jc * 4 + 2][row] = (ushort_t)(v.y & 0xffff);
        T[jc * 4 + 3][row] = (ushort_t)(v.y >> 16);
    }
    __syncthreads();
#pragma unroll
    for (int p = 0; p < 4; ++p) {
        int crow = p * 16 + ir;
        uint2 o;
        o.x = (unsigned)T[crow][jc * 4 + 0] | ((unsigned)T[crow][jc * 4 + 1] << 16);
        o.y = (unsigned)T[crow][jc * 4 + 2] | ((unsigned)T[crow][jc * 4 + 3] << 16);
        *(uint2*)&d[(long)(c0 + crow) * 2048 + r0 + jc * 4] = o;
    }
}

// ---------------- gemm64: 64x64 tile, 4 waves 2x2 of 32x32 ----------------
template <class Epi>
__global__ __launch_bounds__(256, 4) void gemm64(const ushort_t* __restrict__ A, int lda,
                                                 const ushort_t* __restrict__ Bt, int ldb,
                                                 int K, Epi epi) {
    __shared__ ushort_t lA[8 * 66 * 8];
    __shared__ ushort_t lB[8 * 66 * 8];
    const int m0 = blockIdx.x * 64, n0 = blockIdx.y * 64;
    const int t = threadIdx.x;
    const int lane = t & 63, wave = t >> 6;
    const int wm = (wave & 1) * 32, wn = (wave >> 1) * 32;
    const int q = lane >> 4, lm = lane & 15;
    const int r0 = t >> 3, kc = t & 7;
    const int r1 = 32 + r0;
    const int4* pa0 = (const int4*)(A + (long)(m0 + r0) * lda + kc * 8);
    const int4* pa1 = (const int4*)(A + (long)(m0 + r1) * lda + kc * 8);
    const int4* pb0 = (const int4*)(Bt + (long)(n0 + r0) * ldb + kc * 8);
    const int4* pb1 = (const int4*)(Bt + (long)(n0 + r1) * ldb + kc * 8);
    f32x4 zero = {0.f, 0.f, 0.f, 0.f};
    f32x4 acc[2][2];
    acc[0][0] = zero; acc[0][1] = zero; acc[1][0] = zero; acc[1][1] = zero;
    int4 ra0 = pa0[0], ra1 = pa1[0], rb0 = pb0[0], rb1 = pb1[0];
    const int nkt = K >> 6;
    for (int kt = 0; kt < nkt; ++kt) {
        __syncthreads();
        *(int4*)&lA[(kc * 66 + r0) * 8] = ra0;
        *(int4*)&lA[(kc * 66 + r1) * 8] = ra1;
        *(int4*)&lB[(kc * 66 + r0) * 8] = rb0;
        *(int4*)&lB[(kc * 66 + r1) * 8] = rb1;
        __syncthreads();
        if (kt + 1 < nkt) {
            ra0 = pa0[(kt + 1) * 8]; ra1 = pa1[(kt + 1) * 8];
            rb0 = pb0[(kt + 1) * 8]; rb1 = pb1[(kt + 1) * 8];
        }
#pragma unroll
        for (int kk = 0; kk < 2; ++kk) {
            bf16x8 af[2], bfr[2];
#pragma unroll
            for (int mi = 0; mi < 2; ++mi)
                af[mi] = *(const bf16x8*)&lA[((kk * 4 + q) * 66 + wm + mi * 16 + lm) * 8];
#pragma unroll
            for (int ni = 0; ni < 2; ++ni)
                bfr[ni] = *(const bf16x8*)&lB[((kk * 4 + q) * 66 + wn + ni * 16 + lm) * 8];
#pragma unroll
            for (int mi = 0; mi < 2; ++mi)
#pragma unroll
                for (int ni = 0; ni < 2; ++ni)
                    acc[mi][ni] = __builtin_amdgcn_mfma_f32_16x16x32_bf16(af[mi], bfr[ni], acc[mi][ni], 0, 0, 0);
        }
    }
#pragma unroll
    for (int mi = 0; mi < 2; ++mi)
#pragma unroll
        for (int ni = 0; ni < 2; ++ni)
#pragma unroll
            for (int r2 = 0; r2 < 4; ++r2) {
                int row = m0 + wm + mi * 16 + q * 4 + r2;
                int col = n0 + wn + ni * 16 + lm;
                epi(row, col, acc[mi][ni][r2]);
            }
}

struct GeU {
    ushort_t* dst; const float* bias;
    __device__ void operator()(int r, int c, float v) const {
        dst[(long)r * 256 + c] = f2bf(v + bias[c]);
    }
};
struct GeH {
    float* dst; const float* bias;
    __device__ void operator()(int r, int c, float v) const {
        dst[(long)r * 512 + c] = v + bias[c];
    }
};
struct GeD {
    ushort_t* dst; const float* bias; const float* x0; const float* x1;
    __device__ void operator()(int r, int c, float v) const {
        float rx = (r < 8192) ? x0[(long)r * 256 + c] : x1[(long)(r - 8192) * 256 + c];
        dst[(long)r * 256 + c] = f2bf(v + bias[c] + rx);
    }
};
struct GeMd {
    ushort_t* dst; const float* bias;
    __device__ void operator()(int r, int c, float v) const {
        dst[(long)r * 256 + c] = f2bf((v + bias[c]) * 0.25f);
    }
};

// ---------------- fused m-GEMM: softmax(adj) @ u -> cat bf16 ----------------
// grid (64 mtiles of 32 rows, 1, 8): z<4 -> m0 (fp32 adj + rlse), z>=4 -> m1 (bf16 adjT + clse)
// B (ut) staged via global_load_lds DMA (no staging VGPRs).
__global__ __launch_bounds__(256, 2) void gemm_madj(
    const float* __restrict__ adj, const ushort_t* __restrict__ At10,
    const ushort_t* __restrict__ ut, const float* __restrict__ rlse,
    const float* __restrict__ clse, ushort_t* __restrict__ cat) {
    __shared__ ushort_t lA[8 * 34 * 8];
    __shared__ ushort_t lB[8 * 258 * 8];  // layout: granule (kc*258 + d), 16B each
    const int z = blockIdx.z, b = z & 3, side = z >> 2;
    const int m0 = blockIdx.x * 32;
    const int t = threadIdx.x;
    const int lane = t & 63, wave = t >> 6;
    const int q = lane >> 4, lm = lane & 15;
    const int d0 = wave * 64;
    const float* rs = (side == 0 ? rlse : clse) + b * 2048 + m0;
    // B DMA addressing: lane covers ut row d0+lane, chunk kc (16B)
    const ushort_t* gB = ut + (long)z * 524288 + (long)(d0 + lane) * 2048;
    ushort_t* lBl = lB + ((long)d0 + lane) * 8;
    // A addressing
    const int ar = t >> 4, ac4 = t & 15;
    const float* paf[2];
    float rlf[2];
#pragma unroll
    for (int i = 0; i < 2; ++i) {
        paf[i] = adj + ((long)(b * 2048 + m0 + i * 16 + ar)) * 2048 + ac4 * 4;
        rlf[i] = rs[i * 16 + ar];
    }
    const int tr0 = t >> 3, tkc = t & 7;
    const int4* pat = (const int4*)(At10 + ((long)(b * 2048 + m0 + tr0)) * 2048 + tkc * 8);
    float rlt = rs[tr0];

    f32x4 zero = {0.f, 0.f, 0.f, 0.f};
    f32x4 acc[2][4];
#pragma unroll
    for (int mi = 0; mi < 2; ++mi)
#pragma unroll
        for (int ni = 0; ni < 4; ++ni) acc[mi][ni] = zero;

    float4 raf[2];
    int4 rat;
    if (side == 0) {
#pragma unroll
        for (int i = 0; i < 2; ++i) raf[i] = *(const float4*)(paf[i]);
    } else {
        rat = pat[0];
    }
    for (int kt = 0; kt < 32; ++kt) {
        __syncthreads();
        // B: DMA 32KB tile into LDS (8 chunks per wave, lane-contiguous granules)
#pragma unroll
        for (int kc = 0; kc < 8; ++kc)
            gload_lds16(gB + kt * 64 + kc * 8, lBl + (long)kc * 258 * 8);
        // A: exp-transform in registers -> LDS
        if (side == 0) {
#pragma unroll
            for (int i = 0; i < 2; ++i) {
                float4 v = raf[i];
                float rl = rlf[i];
                uint2 o;
                o.x = (unsigned)f2bf(__expf(v.x - rl)) | ((unsigned)f2bf(__expf(v.y - rl)) << 16);
                o.y = (unsigned)f2bf(__expf(v.z - rl)) | ((unsigned)f2bf(__expf(v.w - rl)) << 16);
                *(uint2*)&lA[((ac4 >> 1) * 34 + i * 16 + ar) * 8 + (ac4 & 1) * 4] = o;
            }
        } else {
            int4 w = rat;
            float rl = rlt;
            unsigned u[4] = {(unsigned)w.x, (unsigned)w.y, (unsigned)w.z, (unsigned)w.w};
            uint2 o0, o1;
            o0.x = (unsigned)f2bf(__expf(bf2f((ushort_t)(u[0] & 0xffff)) - rl)) |
                   ((unsigned)f2bf(__expf(bf2f((ushort_t)(u[0] >> 16)) - rl)) << 16);
            o0.y = (unsigned)f2bf(__expf(bf2f((ushort_t)(u[1] & 0xffff)) - rl)) |
                   ((unsigned)f2bf(__expf(bf2f((ushort_t)(u[1] >> 16)) - rl)) << 16);
            o1.x = (unsigned)f2bf(__expf(bf2f((ushort_t)(u[2] & 0xffff)) - rl)) |
                   ((unsigned)f2bf(__expf(bf2f((ushort_t)(u[2] >> 16)) - rl)) << 16);
            o1.y = (unsigned)f2bf(__expf(bf2f((ushort_t)(u[3] & 0xffff)) - rl)) |
                   ((unsigned)f2bf(__expf(bf2f((ushort_t)(u[3] >> 16)) - rl)) << 16);
            *(uint2*)&lA[(tkc * 34 + tr0) * 8] = o0;
            *(uint2*)&lA[(tkc * 34 + tr0) * 8 + 4] = o1;
        }
        __syncthreads();  // drains DMA (vmcnt) + A writes (lgkmcnt)
        // A prefetch for next iter
        if (kt + 1 < 32) {
            if (side == 0) {
#pragma unroll
                for (int i = 0; i < 2; ++i) raf[i] = *(const float4*)(paf[i] + (kt + 1) * 64);
            } else {
                rat = pat[(kt + 1) * 8];
            }
        }
#pragma unroll
        for (int kk = 0; kk < 2; ++kk) {
            bf16x8 af[2], bfr[4];
#pragma unroll
            for (int mi = 0; mi < 2; ++mi)
                af[mi] = *(const bf16x8*)&lA[((kk * 4 + q) * 34 + mi * 16 + lm) * 8];
#pragma unroll
            for (int ni = 0; ni < 4; ++ni)
                bfr[ni] = *(const bf16x8*)&lB[((kk * 4 + q) * 258 + wave * 64 + ni * 16 + lm) * 8];
#pragma unroll
            for (int mi = 0; mi < 2; ++mi)
#pragma unroll
                for (int ni = 0; ni < 4; ++ni)
                    acc[mi][ni] = __builtin_amdgcn_mfma_f32_16x16x32_bf16(af[mi], bfr[ni], acc[mi][ni], 0, 0, 0);
        }
    }
    // epilogue: stage 32x256 bf16 in LDS (stride 264), then coalesced 16B stores
    __syncthreads();
    ushort_t* stg = lB;
#pragma unroll
    for (int mi = 0; mi < 2; ++mi)
#pragma unroll
        for (int ni = 0; ni < 4; ++ni)
#pragma unroll
            for (int r2 = 0; r2 < 4; ++r2) {
                int row = mi * 16 + q * 4 + r2;
                int col = wave * 64 + ni * 16 + lm;
                stg[row * 264 + col] = f2bf(acc[mi][ni][r2]);
            }
    __syncthreads();
    {
        int row = t >> 3, ch = t & 7;
        long g = ((long)(z * 2048 + m0 + row)) * 512 + 256 + ch * 32;
#pragma unroll
        for (int j = 0; j < 4; ++j)
            *(int4*)&cat[g + j * 8] = *(const int4*)&stg[row * 264 + ch * 32 + j * 8];
    }
}

// ---------------- sim GEMM: md0 @ md1^T (128x128 tile) + fused LSE partials ----------------
// grid (16 mtiles, 16 ntiles, 4 b)
__global__ __launch_bounds__(256, 2) void gemm_sim(
    const ushort_t* __restrict__ mdb, ushort_t* __restrict__ simb,
    float* __restrict__ rpm, float* __restrict__ rps,
    float* __restrict__ cpm, float* __restrict__ cps) {
    __shared__ ushort_t lA[8 * 130 * 8];
    __shared__ ushort_t lB[8 * 130 * 8];
    __shared__ ushort_t stg[128 * 136];
    __shared__ float rsm[128][2], rss[128][2], csm[128][2], css[128][2];
    const int b = blockIdx.z;
    const int m0 = blockIdx.x * 128, n0 = blockIdx.y * 128;
    const ushort_t* A = mdb + (long)b * 524288;
    const ushort_t* Bt = mdb + (long)(4 + b) * 524288;
    const int t = threadIdx.x;
    const int lane = t & 63, wave = t >> 6;
    const int wm = (wave & 1) * 64, wn = (wave >> 1) * 64;
    const int q = lane >> 4, lm = lane & 15;
    const int4* pa[4];
    const int4* pb[4];
    int arow[4], akc[4];
#pragma unroll
    for (int i = 0; i < 4; ++i) {
        int c = i * 256 + t;
        arow[i] = c >> 3;
        akc[i] = c & 7;
        pa[i] = (const int4*)(A + (long)(m0 + arow[i]) * 256 + akc[i] * 8);
        pb[i] = (const int4*)(Bt + (long)(n0 + arow[i]) * 256 + akc[i] * 8);
    }
    f32x4 zero = {0.f, 0.f, 0.f, 0.f};
    f32x4 acc[4][4];
#pragma unroll
    for (int mi = 0; mi < 4; ++mi)
#pragma unroll
        for (int ni = 0; ni < 4; ++ni) acc[mi][ni] = zero;
    int4 ra[4], rb[4];
#pragma unroll
    for (int i = 0; i < 4; ++i) { ra[i] = pa[i][0]; rb[i] = pb[i][0]; }
    for (int kt = 0; kt < 4; ++kt) {
        __syncthreads();
#pragma unroll
        for (int i = 0; i < 4; ++i) {
            *(int4*)&lA[(akc[i] * 130 + arow[i]) * 8] = ra[i];
            *(int4*)&lB[(akc[i] * 130 + arow[i]) * 8] = rb[i];
        }
        __syncthreads();
        if (kt + 1 < 4) {
#pragma unroll
            for (int i = 0; i < 4; ++i) { ra[i] = pa[i][(kt + 1) * 8]; rb[i] = pb[i][(kt + 1) * 8]; }
        }
#pragma unroll
        for (int kk = 0; kk < 2; ++kk) {
            bf16x8 af[4], bfr[4];
#pragma unroll
            for (int mi = 0; mi < 4; ++mi)
                af[mi] = *(const bf16x8*)&lA[((kk * 4 + q) * 130 + wm + mi * 16 + lm) * 8];
#pragma unroll
            for (int ni = 0; ni < 4; ++ni)
                bfr[ni] = *(const bf16x8*)&lB[((kk * 4 + q) * 130 + wn + ni * 16 + lm) * 8];
#pragma unroll
            for (int mi = 0; mi < 4; ++mi)
#pragma unroll
                for (int ni = 0; ni < 4; ++ni)
                    acc[mi][ni] = __builtin_amdgcn_mfma_f32_16x16x32_bf16(af[mi], bfr[ni], acc[mi][ni], 0, 0, 0);
        }
    }
    // row (max,sumexp) partials over this block's 128 cols
#pragma unroll
    for (int mi = 0; mi < 4; ++mi)
#pragma unroll
        for (int r2 = 0; r2 < 4; ++r2) {
            float mx = acc[mi][0][r2], sm = 1.f;
#pragma unroll
            for (int ni = 1; ni < 4; ++ni) msmerge(mx, sm, acc[mi][ni][r2], 1.f);
#pragma unroll
            for (int o = 1; o < 16; o <<= 1) {
                float om = __shfl_xor(mx, o, 64);
                float os = __shfl_xor(sm, o, 64);
                msmerge(mx, sm, om, os);
            }
            if (lm == 0) {
                int row = wm + mi * 16 + q * 4 + r2;
                rsm[row][wn >> 6] = mx; rss[row][wn >> 6] = sm;
            }
        }
    // col (max,sumexp) partials over this block's 128 rows
#pragma unroll
    for (int ni = 0; ni < 4; ++ni) {
        float mx = acc[0][ni][0], sm = 1.f;
#pragma unroll
        for (int mi = 0; mi < 4; ++mi)
#pragma unroll
            for (int r2 = 0; r2 < 4; ++r2) {
                if (mi == 0 && r2 == 0) continue;
                msmerge(mx, sm, acc[mi][ni][r2], 1.f);
            }
#pragma unroll
        for (int o = 16; o < 64; o <<= 1) {
            float om = __shfl_xor(mx, o, 64);
            float os = __shfl_xor(sm, o, 64);
            msmerge(mx, sm, om, os);
        }
        if (q == 0) {
            int col = wn + ni * 16 + lm;
            csm[col][wm >> 6] = mx; css[col][wm >> 6] = sm;
        }
    }
    // stage bf16 output
#pragma unroll
    for (int mi = 0; mi < 4; ++mi)
#pragma unroll
        for (int ni = 0; ni < 4; ++ni)
#pragma unroll
            for (int r2 = 0; r2 < 4; ++r2)
                stg[(wm + mi * 16 + q * 4 + r2) * 136 + wn + ni * 16 + lm] = f2bf(acc[mi][ni][r2]);
    __syncthreads();
    if (t < 128) {
        float m = rsm[t][0], s = rss[t][0];
        msmerge(m, s, rsm[t][1], rss[t][1]);
        int idx = (b * 16 + blockIdx.y) * 2048 + m0 + t;
        rpm[idx] = m; rps[idx] = s;
    } else {
        int c = t - 128;
        float m = csm[c][0], s = css[c][0];
        msmerge(m, s, csm[c][1], css[c][1]);
        int idx = (b * 16 + blockIdx.x) * 2048 + n0 + c;
        cpm[idx] = m; cps[idx] = s;
    }
    {
        int row = t >> 1, half = t & 1;
        long g = (long)b * 4194304 + (long)(m0 + row) * 2048 + n0 + half * 64;
#pragma unroll
        for (int j = 0; j < 8; ++j)
            *(int4*)&simb[g + j * 8] = *(const int4*)&stg[row * 136 + half * 64 + j * 8];
    }
}

// ---------------- LN + GELU (rows of 512) ----------------
__global__ void k_ln(const float* __restrict__ h, const float* __restrict__ lng,
                     const float* __restrict__ lnb, ushort_t* __restrict__ out) {
    int row = blockIdx.x;
    int t = threadIdx.x;
    const float* p = h + (long)row * 512;
    float a = p[t], c = p[t + 256];
    float s = wredsum(a + c);
    __shared__ float sh[4];
    if ((t & 63) == 0) sh[t >> 6] = s;
    __syncthreads();
    float mean = (sh[0] + sh[1] + sh[2] + sh[3]) * (1.f / 512.f);
    float da = a - mean, dc = c - mean;
    float s2 = wredsum(da * da + dc * dc);
    __shared__ float sh2[4];
    if ((t & 63) == 0) sh2[t >> 6] = s2;
    __syncthreads();
    float var = (sh2[0] + sh2[1] + sh2[2] + sh2[3]) * (1.f / 512.f);
    float inv = rsqrtf(var + 1e-5f);
    float x1 = da * inv * lng[t] + lnb[t];
    float x2 = dc * inv * lng[t + 256] + lnb[t + 256];
    float g1 = 0.5f * x1 * (1.f + erff(x1 * 0.70710678118654752f));
    float g2 = 0.5f * x2 * (1.f + erff(x2 * 0.70710678118654752f));
    out[(long)row * 512 + t] = f2bf(g1);
    out[(long)row * 512 + t + 256] = f2bf(g2);
}

// ---------------- z = d @ Wz + bz -> log_sigmoid(+-z); 16384 merged rows ----------------
__global__ void k_z(const ushort_t* __restrict__ dmat, const float* __restrict__ Wz,
                    const float* __restrict__ bzp, float* __restrict__ lszp,
                    float* __restrict__ lszn) {
    int row = blockIdx.x * 4 + (threadIdx.x >> 6);
    int l = threadIdx.x & 63;
    const ushort_t* p = dmat + (long)row * 256 + l * 4;
    float4 w = *(const float4*)(Wz + l * 4);
    float s = bf2f(p[0]) * w.x + bf2f(p[1]) * w.y + bf2f(p[2]) * w.z + bf2f(p[3]) * w.w;
    s = wredsum(s);
    if (l == 0) {
        float z = s + bzp[0];
        lszp[row] = logsig(z);
        lszn[row] = logsig(-z);
    }
}

// ---------------- fused: transform simb -> scores, row max/argmax, col-argmax partials ----------------
// grid 512: b = blk>>7, chunk of 16 rows = blk&127
__global__ void k_scores2(const ushort_t* __restrict__ simb, float* __restrict__ scores,
                          const float* __restrict__ rowLSE, const float* __restrict__ colLSE,
                          const float* __restrict__ lszp, const float* __restrict__ lszn,
                          float* __restrict__ rmax, int* __restrict__ ridx,
                          float* __restrict__ pcv, int* __restrict__ pci) {
    int blk = blockIdx.x;
    int b = blk >> 7, ch = blk & 127;
    int t = threadIdx.x;
    int lane = t & 63, wave = t >> 6;
    int n0 = t * 8;
    const float* cl = colLSE + b * 2048;
    const float* l1p = lszp + 8192 + b * 2048;
    float clv[8], l1v[8];
#pragma unroll
    for (int j = 0; j < 8; ++j) { clv[j] = cl[n0 + j]; l1v[j] = l1p[n0 + j]; }
    float cbv[8];
    int cbi[8];
#pragma unroll
    for (int j = 0; j < 8; ++j) { cbv[j] = -3.4e38f; cbi[j] = 0; }
    __shared__ float rv[16][4];
    __shared__ int ri[16][4];
    for (int r = 0; r < 16; ++r) {
        int m = ch * 16 + r;
        int gm = b * 2048 + m;
        float rl = rowLSE[gm], l0 = lszp[gm];
        float base = l0 - rl;
        int4 w = *(const int4*)&simb[(long)b * 4194304 + (long)m * 2048 + n0];
        unsigned u[4] = {(unsigned)w.x, (unsigned)w.y, (unsigned)w.z, (unsigned)w.w};
        float* dst = scores + (long)b * 4198401 + (long)m * 2049 + n0;
        float bv = -3.4e38f;
        int bi = 0;
#pragma unroll
        for (int i = 0; i < 4; ++i) {
#pragma unroll
            for (int h = 0; h < 2; ++h) {
                int j = i * 2 + h;
                float sv = bf2f((ushort_t)(h ? (u[i] >> 16) : (u[i] & 0xffff)));
                float tv = 2.f * sv + base;
                float v = tv - clv[j] + l1v[j];
                dst[j] = v;
                if (v > bv) { bv = v; bi = n0 + j; }
                if (tv > cbv[j]) { cbv[j] = tv; cbi[j] = m; }
            }
        }
        for (int o = 32; o; o >>= 1) {
            float ov = __shfl_xor(bv, o, 64);
            int oi = __shfl_xor(bi, o, 64);
            if (ov > bv || (ov == bv && oi < bi)) { bv = ov; bi = oi; }
        }
        if (lane == 0) { rv[r][wave] = bv; ri[r][wave] = bi; }
    }
    __syncthreads();
    if (t < 16) {
        float bv = rv[t][0];
        int bi = ri[t][0];
        for (int w2 = 1; w2 < 4; ++w2)
            if (rv[t][w2] > bv || (rv[t][w2] == bv && ri[t][w2] < bi)) { bv = rv[t][w2]; bi = ri[t][w2]; }
        int gm = b * 2048 + ch * 16 + t;
        rmax[gm] = bv;
        ridx[gm] = bi;
        scores[(long)b * 4198401 + (long)(ch * 16 + t) * 2049 + 2048] = lszn[gm];
    }
    long pidx = (long)(b * 128 + ch) * 2048 + n0;
#pragma unroll
    for (int j = 0; j < 8; ++j) { pcv[pidx + j] = cbv[j]; pci[pidx + j] = cbi[j]; }
}

// ---------------- combine col argmax chunks, write border row + corner ----------------
__global__ void k_colmaxB(const float* __restrict__ pcv, const int* __restrict__ pci,
                          const float* __restrict__ lszn, float* __restrict__ scores,
                          int* __restrict__ cidx) {
    int idx = blockIdx.x * 256 + threadIdx.x;  // 8192
    int b = idx >> 11, n = idx & 2047;
    float bv = -3.4e38f;
    int bi = 0;
    for (int c = 0; c < 128; ++c) {
        float v = pcv[(long)(b * 128 + c) * 2048 + n];
        int i = pci[(long)(b * 128 + c) * 2048 + n];
        if (v > bv || (v == bv && i < bi)) { bv = v; bi = i; }
    }
    cidx[idx] = bi;
    scores[(long)b * 4198401 + 2048L * 2049 + n] = lszn[8192 + idx];
    if (n == 0) scores[(long)b * 4198401 + 2048L * 2049 + 2048] = 0.f;
}

__global__ void k_match0(const int* __restrict__ ridx, const int* __restrict__ cidx,
                         const float* __restrict__ rmax, float* __restrict__ m0out,
                         float* __restrict__ ms0out, float* __restrict__ ms0ws,
                         int* __restrict__ v0ws) {
    int idx = blockIdx.x * 256 + threadIdx.x;
    int b = idx >> 11, m = idx & 2047;
    int j = ridx[idx];
    bool mutual = (cidx[b * 2048 + j] == m);
    float e = mutual ? expf(rmax[idx]) : 0.f;
    bool valid = mutual && (e > 0.1f);
    m0out[idx] = valid ? (float)j : -1.f;
    ms0out[idx] = e;
    ms0ws[idx] = e;
    v0ws[idx] = valid ? 1 : 0;
}

__global__ void k_match1(const int* __restrict__ cidx, const int* __restrict__ ridx,
                         const float* __restrict__ ms0ws, const int* __restrict__ v0ws,
                         float* __restrict__ m1out, float* __restrict__ ms1out) {
    int idx = blockIdx.x * 256 + threadIdx.x;
    int b = idx >> 11, n = idx & 2047;
    int j = cidx[idx];
    bool mutual = (ridx[b * 2048 + j] == n);
    float ms1 = mutual ? ms0ws[b * 2048 + j] : 0.f;
    bool valid = mutual && (v0ws[b * 2048 + j] != 0);
    m1out[idx] = valid ? (float)j : -1.f;
    ms1out[idx] = ms1;
}

extern "C" void kernel_launch(void* const* d_in, const int* in_sizes, int n_in,
                              void* d_out, int out_size, void* d_ws, size_t ws_size,
                              hipStream_t stream) {
    (void)in_sizes; (void)n_in; (void)out_size; (void)ws_size;
    const float* x0  = (const float*)d_in[0];
    const float* x1  = (const float*)d_in[1];
    const float* adj = (const float*)d_in[2];
    const float* Wv  = (const float*)d_in[3];
    const float* bv  = (const float*)d_in[4];
    const float* Wo  = (const float*)d_in[5];
    const float* bo  = (const float*)d_in[6];
    const float* Wf1 = (const float*)d_in[7];
    const float* bf1 = (const float*)d_in[8];
    const float* lng = (const float*)d_in[9];
    const float* lnb = (const float*)d_in[10];
    const float* Wf2 = (const float*)d_in[11];
    const float* bf2 = (const float*)d_in[12];
    const float* Wfp = (const float*)d_in[13];
    const float* bfp = (const float*)d_in[14];
    const float* Wz  = (const float*)d_in[15];
    const float* bz  = (const float*)d_in[16];

    float* out = (float*)d_out;
    float* scores  = out;
    float* out_m0  = out + 16793604;
    float* out_m1  = out_m0 + 8192;
    float* out_ms0 = out_m1 + 8192;
    float* out_ms1 = out_ms0 + 8192;

    char* base = (char*)d_ws;
    // [0, 33.5M): At10 raw bf16 (prep->madj), then hbuf fp32 (h-gemm->ln)
    ushort_t* At10 = (ushort_t*)base;
    float*    hbuf = (float*)base;
    // [33.5M, 67M): simb bf16 (sim-gemm -> scores2)
    ushort_t* simb = (ushort_t*)(base + 33554432);
    size_t off = 67108864;
    auto alloc = [&](size_t sz) { char* p = base + off; off += (sz + 255) & ~(size_t)255; return p; };
    ushort_t* cat  = (ushort_t*)alloc(16777216);   // 16384x512 bf16
    ushort_t* ubuf = (ushort_t*)alloc(8388608);    // 16384x256 bf16 ; later pcv (4MB)
    ushort_t* ut   = (ushort_t*)alloc(8388608);    // 8 slabs 256x2048 ; later pci (4MB)
    ushort_t* gbuf = (ushort_t*)alloc(16777216);   // 16384x512 bf16
    ushort_t* dbuf = (ushort_t*)alloc(8388608);    // 16384x256 bf16
    ushort_t* mdb  = (ushort_t*)alloc(8388608);    // 16384x256 bf16
    ushort_t* Wovb = (ushort_t*)alloc(131072);
    ushort_t* Wf1b = (ushort_t*)alloc(524288);
    ushort_t* Wf2b = (ushort_t*)alloc(262144);
    ushort_t* Wfpb = (ushort_t*)alloc(131072);
    float* bvo     = (float*)alloc(1024);
    float* rowm    = (float*)alloc(1048576);
    float* rows_   = (float*)alloc(1048576);
    float* colm    = (float*)alloc(1048576);
    float* cols_   = (float*)alloc(1048576);
    float* rlse    = (float*)alloc(32768);
    float* clse    = (float*)alloc(32768);
    float* rpm     = (float*)alloc(524288);
    float* rps     = (float*)alloc(524288);
    float* cpm     = (float*)alloc(524288);
    float* cps     = (float*)alloc(524288);
    float* rowLSE  = (float*)alloc(32768);
    float* colLSE  = (float*)alloc(32768);
    float* rmax    = (float*)alloc(32768);
    int*   ridx    = (int*)alloc(32768);
    int*   cidx    = (int*)alloc(32768);
    float* lszp    = (float*)alloc(65536);
    float* lszn    = (float*)alloc(65536);
    float* ms0ws   = (float*)alloc(32768);
    int*   v0ws    = (int*)alloc(32768);
    float* pcv = (float*)ubuf;   // overlay: ubuf dead after k_tr
    int*   pci = (int*)ut;       // overlay: ut dead after gemm_madj

    // ---- weight prep + casts ----
    k_wov<<<256, 256, 0, stream>>>(Wo, Wv, bv, bo, Wovb, bvo);
    k_cast_flat<<<1024, 256, 0, stream>>>(Wf1, Wf1b, 262144);
    k_cast_flat<<<512, 256, 0, stream>>>(Wf2, Wf2b, 131072);
    k_cast_flat<<<256, 256, 0, stream>>>(Wfp, Wfpb, 65536);
    k_cast_x<<<8192, 256, 0, stream>>>(x0, cat);
    k_cast_x<<<8192, 256, 0, stream>>>(x1, cat + 8192L * 512);

    // ---- adjacency: raw transpose + fused LSE partials ----
    k_prep<<<dim3(32, 32, 4), 256, 0, stream>>>(adj, At10, rowm, rows_, colm, cols_);
    k_statcomb<<<32, 256, 0, stream>>>(rowm, rows_, 32, rlse);
    k_statcomb<<<32, 256, 0, stream>>>(colm, cols_, 32, clse);

    // ---- u = x @ Wov.T + bvo, then transpose slab-swapped ----
    gemm64<<<dim3(256, 4), 256, 0, stream>>>(cat, 512, Wovb, 256, 256, GeU{ubuf, bvo});
    k_tr<<<dim3(4, 32, 8), 256, 0, stream>>>(ubuf, ut);

    // ---- fused m = softmax(adj) @ u -> cat[...,256:512] ----
    gemm_madj<<<dim3(64, 1, 8), 256, 0, stream>>>(adj, At10, ut, rlse, clse, cat);

    // ---- h = cat @ Wf1.T + bf1 ----
    gemm64<<<dim3(256, 8), 256, 0, stream>>>(cat, 512, Wf1b, 512, 512, GeH{hbuf, bf1});
    k_ln<<<16384, 256, 0, stream>>>(hbuf, lng, lnb, gbuf);

    // ---- d = x + g @ Wf2.T + bf2 ----
    gemm64<<<dim3(256, 4), 256, 0, stream>>>(gbuf, 512, Wf2b, 512, 512, GeD{dbuf, bf2, x0, x1});

    // ---- z / log_sigmoid ----
    k_z<<<4096, 256, 0, stream>>>(dbuf, Wz, bz, lszp, lszn);

    // ---- md = (d @ Wfp.T + bfp)/4 ----
    gemm64<<<dim3(256, 4), 256, 0, stream>>>(dbuf, 256, Wfpb, 256, 256, GeMd{mdb, bfp});

    // ---- sim = md0 @ md1^T -> simb bf16, with fused row/col LSE partials ----
    gemm_sim<<<dim3(16, 16, 4), 256, 0, stream>>>(mdb, simb, rpm, rps, cpm, cps);
    k_statcomb<<<32, 256, 0, stream>>>(rpm, rps, 16, rowLSE);
    k_statcomb<<<32, 256, 0, stream>>>(cpm, cps, 16, colLSE);

    // ---- transform + row argmax + col-argmax partials ----
    k_scores2<<<512, 256, 0, stream>>>(simb, scores, rowLSE, colLSE, lszp, lszn,
                                       rmax, ridx, pcv, pci);
    k_colmaxB<<<32, 256, 0, stream>>>(pcv, pci, lszn, scores, cidx);

    // ---- mutual matching ----
    k_match0<<<32, 256, 0, stream>>>(ridx, cidx, rmax, out_m0, out_ms0, ms0ws, v0ws);
    k_match1<<<32, 256, 0, stream>>>(cidx, ridx, ms0ws, v0ws, out_m1, out_ms1);
}